// Round 6
// baseline (347.762 us; speedup 1.0000x reference)
//
#include <hip/hip_runtime.h>

#define N_ROWS 65536
#define NE 1024
#define E_DIM 64
#define MB 128            // rows per block

// d_out float layout: [0]=loss, [1..4194304]=quantized, [4194305]=perplexity, [4194306..]=encodings
#define Q_OFF 1
#define P_OFF 4194305
#define ENC_OFF 4194306

typedef float f32x2 __attribute__((ext_vector_type(2)));
typedef float f32x4 __attribute__((ext_vector_type(4)));
typedef short bf16x8 __attribute__((ext_vector_type(8)));
typedef unsigned short u16x8 __attribute__((ext_vector_type(8)));

__device__ __forceinline__ short f2bf(float x) {
    union { float f; unsigned u; } v; v.f = x;
    unsigned r = v.u + 0x7FFF + ((v.u >> 16) & 1);   // RNE
    return (short)(r >> 16);
}
__device__ __forceinline__ float bf2f(short h) {
    union { float f; unsigned u; } v; v.u = ((unsigned)(unsigned short)h) << 16;
    return v.f;
}

// ---------------- K0: split-bf16 codebook + 0.5*||e||^2 + zero hist/lacc ----------------
__global__ __launch_bounds__(256) void k0_prep(const float* __restrict__ emb,
                                               ushort* __restrict__ ehi, ushort* __restrict__ elo,
                                               float* __restrict__ enorm,
                                               int* __restrict__ hist, float* __restrict__ lacc) {
    const int t = blockIdx.x * 256 + threadIdx.x;    // 0..4095
    const int code = t >> 2, part = t & 3;           // 4 threads per code, 16 elems each
    const float4* ep = (const float4*)(emb + code * 64 + part * 16);
    float s = 0.f;
    ushort h[16], l[16];
#pragma unroll
    for (int q = 0; q < 4; ++q) {
        float4 v = ep[q];
        float vv[4] = {v.x, v.y, v.z, v.w};
#pragma unroll
        for (int j = 0; j < 4; ++j) {
            float x = vv[j];
            s += x * x;
            short hh = f2bf(x);
            h[q * 4 + j] = (ushort)hh;
            l[q * 4 + j] = (ushort)f2bf(x - bf2f(hh));
        }
    }
    s += __shfl_xor(s, 1); s += __shfl_xor(s, 2);
    u16x8 ha, hb, la, lb;
#pragma unroll
    for (int j = 0; j < 8; ++j) { ha[j] = h[j]; hb[j] = h[8 + j]; la[j] = l[j]; lb[j] = l[8 + j]; }
    u16x8* hp = (u16x8*)(ehi + code * 64 + part * 16);
    u16x8* lp = (u16x8*)(elo + code * 64 + part * 16);
    hp[0] = ha; hp[1] = hb; lp[0] = la; lp[1] = lb;
    if (part == 0) enorm[code] = 0.5f * s;
    if (t < NE) hist[t] = 0;
    if (t == 0) *lacc = 0.f;
}

// ---------------- K1: barrier-free MFMA main loop, B direct from L2 ----------------
__global__ __launch_bounds__(256, 2) void k1_main(
    const float* __restrict__ in, const float* __restrict__ emb,
    const ushort* __restrict__ ehi, const ushort* __restrict__ elo,
    const float* __restrict__ enorm,
    int* __restrict__ hist, float* __restrict__ lacc,
    float* __restrict__ out) {
    __shared__ float lds_en[NE];      // 4 KB
    __shared__ int   lds_idx[MB];
    __shared__ float lds_sc[MB];
    __shared__ float lds_xn[MB];
    __shared__ float lds_part[4];

    const int tid = threadIdx.x;
    const int wave = tid >> 6, lane = tid & 63;
    const int lr = lane & 15, kg = lane >> 4;
    const int r0b = blockIdx.x * MB;
    const int rw = r0b + wave * 32;

    // stage enorm once (the only pre-epilogue barrier; no stores outstanding yet)
    ((float4*)lds_en)[tid] = ((const float4*)enorm)[tid];
    __syncthreads();

    // ---- A-fragment prep: lane holds row (lr), k = kg*8+j per half; split bf16 ----
    bf16x8 ah[2][2], al[2][2];
    float xn[2];
#pragma unroll
    for (int rt = 0; rt < 2; ++rt) {
        const int row = rw + rt * 16 + lr;
        const int base = ((row >> 12) * 262144) + (row & 4095);
        float acc2 = 0.f;
#pragma unroll
        for (int hh = 0; hh < 2; ++hh) {
            float xv[8];
#pragma unroll
            for (int j = 0; j < 8; ++j) xv[j] = in[base + (hh * 32 + kg * 8 + j) * 4096];
            bf16x8 hi8, lo8;
#pragma unroll
            for (int j = 0; j < 8; ++j) {
                acc2 += xv[j] * xv[j];
                short hv = f2bf(xv[j]);
                hi8[j] = hv;
                lo8[j] = f2bf(xv[j] - bf2f(hv));
            }
            ah[rt][hh] = hi8; al[rt][hh] = lo8;
        }
        acc2 += __shfl_xor(acc2, 16);
        acc2 += __shfl_xor(acc2, 32);
        xn[rt] = acc2;
    }

    float best[2][4]; int bidx[2][4];
#pragma unroll
    for (int rt = 0; rt < 2; ++rt)
#pragma unroll
        for (int i = 0; i < 4; ++i) { best[rt][i] = -1e30f; bidx[rt][i] = 0; }

    const bf16x8* eh8 = (const bf16x8*)ehi;
    const bf16x8* el8 = (const bf16x8*)elo;
    f32x2* encb = (f32x2*)(out + ENC_OFF);           // 8B aligned
    const int gb = lr * 8 + kg;                       // element idx at T=0

    // 64 code-tiles of 16; no barriers, stores stream freely
    for (int T0 = 0; T0 < 64; T0 += 8) {
#pragma unroll
        for (int tt = 0; tt < 8; ++tt) {
            const int T = T0 + tt;
            const int ei = T * 128 + gb;
            bf16x8 bh0 = eh8[ei],     bh1 = eh8[ei + 4];
            bf16x8 bl0 = el8[ei],     bl1 = el8[ei + 4];

            // encodings zero-fill: 4 x f32x2 nt stores (rows rr=T>>1, 512 slots/row)
            {
                f32x2* rowp = encb + (size_t)(rw + (T >> 1)) * 512;
                const int s0 = ((4 * T) & 7) * 64 + lane;
                f32x2 z = {0.f, 0.f};
                __builtin_nontemporal_store(z, rowp + s0);
                __builtin_nontemporal_store(z, rowp + s0 + 64);
                __builtin_nontemporal_store(z, rowp + s0 + 128);
                __builtin_nontemporal_store(z, rowp + s0 + 192);
            }

            const float en = lds_en[T * 16 + lr];
            const int code = T * 16 + lr;
#pragma unroll
            for (int rt = 0; rt < 2; ++rt) {
                f32x4 acc = {0.f, 0.f, 0.f, 0.f};
                acc = __builtin_amdgcn_mfma_f32_16x16x32_bf16(al[rt][0], bh0, acc, 0, 0, 0);
                acc = __builtin_amdgcn_mfma_f32_16x16x32_bf16(al[rt][1], bh1, acc, 0, 0, 0);
                acc = __builtin_amdgcn_mfma_f32_16x16x32_bf16(ah[rt][0], bl0, acc, 0, 0, 0);
                acc = __builtin_amdgcn_mfma_f32_16x16x32_bf16(ah[rt][1], bl1, acc, 0, 0, 0);
                acc = __builtin_amdgcn_mfma_f32_16x16x32_bf16(ah[rt][0], bh0, acc, 0, 0, 0);
                acc = __builtin_amdgcn_mfma_f32_16x16x32_bf16(ah[rt][1], bh1, acc, 0, 0, 0);
#pragma unroll
                for (int i = 0; i < 4; ++i) {
                    float sc = acc[i] - en;
                    if (sc > best[rt][i]) { best[rt][i] = sc; bidx[rt][i] = code; }
                }
            }
        }
    }

    // ---- cross-lane argmin over the 16 codes per tile-slice ----
#pragma unroll
    for (int mask = 1; mask <= 8; mask <<= 1) {
#pragma unroll
        for (int rt = 0; rt < 2; ++rt)
#pragma unroll
            for (int i = 0; i < 4; ++i) {
                float os = __shfl_xor(best[rt][i], mask);
                int   oi = __shfl_xor(bidx[rt][i], mask);
                if (os > best[rt][i] || (os == best[rt][i] && oi < bidx[rt][i])) {
                    best[rt][i] = os; bidx[rt][i] = oi;
                }
            }
    }
    if (lr == 0) {
#pragma unroll
        for (int rt = 0; rt < 2; ++rt)
#pragma unroll
            for (int i = 0; i < 4; ++i) {
                int rl = wave * 32 + rt * 16 + kg * 4 + i;
                lds_idx[rl] = bidx[rt][i];
                lds_sc[rl] = best[rt][i];
            }
    }
    if (kg == 0) {
#pragma unroll
        for (int rt = 0; rt < 2; ++rt) lds_xn[wave * 32 + rt * 16 + lane] = xn[rt];
    }
    __syncthreads();   // also drains all zero stores (vmcnt 0) before the '1' writes

    // ---- loss + histogram ----
    float dm = 0.f;
    if (tid < MB) {
        int idx = lds_idx[tid];
        dm = lds_xn[tid] - 2.f * lds_sc[tid];
        atomicAdd(&hist[idx], 1);
    }
#pragma unroll
    for (int off = 32; off; off >>= 1) dm += __shfl_down(dm, off);
    if (lane == 0) lds_part[wave] = dm;
    __syncthreads();
    if (tid == 0) atomicAdd(lacc, (lds_part[0] + lds_part[1]) + (lds_part[2] + lds_part[3]));

    // ---- the '1' per encodings row (same lane & same 8B chunk as its zero store) ----
    for (int rr = 0; rr < 32; ++rr) {
        int rl = wave * 32 + rr;
        int idx = lds_idx[rl];
        if (lane == ((idx >> 1) & 63)) {
            f32x2 v;
            v.x = (idx & 1) ? 0.f : 1.f;
            v.y = (idx & 1) ? 1.f : 0.f;
            __builtin_nontemporal_store(v,
                encb + (size_t)(r0b + rl) * 512 + (idx >> 1));
        }
    }

    // ---- quantized gather (exact fp32 from emb) ----
    const float4* emb4 = (const float4*)emb;
#pragma unroll
    for (int i = 0; i < 8; ++i) {
        int lin = i * 256 + tid;              // 0..2047
        int rl = lin & 127, cq = lin >> 7;    // cq 0..15
        int idx = lds_idx[rl];
        float4 v = emb4[idx * 16 + cq];
        int row = r0b + rl;
        int qb = Q_OFF + ((row >> 12) * 262144) + (row & 4095);
        out[qb + (cq * 4 + 0) * 4096] = v.x;
        out[qb + (cq * 4 + 1) * 4096] = v.y;
        out[qb + (cq * 4 + 2) * 4096] = v.z;
        out[qb + (cq * 4 + 3) * 4096] = v.w;
    }
}

// ---------------- K3: scalars ----------------
__global__ __launch_bounds__(256) void k3_final(const int* __restrict__ hist,
                                                const float* __restrict__ lacc,
                                                float* __restrict__ out) {
    __shared__ float lsum[4];
    const int tid = threadIdx.x;
    float s = 0.f;
#pragma unroll
    for (int k = 0; k < 4; ++k) {
        float p = (float)hist[k * 256 + tid] * (1.0f / 65536.f);
        s += p * logf(p + 1e-10f);
    }
#pragma unroll
    for (int off = 32; off; off >>= 1) s += __shfl_down(s, off);
    if ((tid & 63) == 0) lsum[tid >> 6] = s;
    __syncthreads();
    if (tid == 0) {
        float ent = (lsum[0] + lsum[1]) + (lsum[2] + lsum[3]);
        out[P_OFF] = expf(-ent);
        out[0] = *lacc * (1.25f / 4194304.f);   // (1+beta)*mean; q_loss==e_loss in value
    }
}

extern "C" void kernel_launch(void* const* d_in, const int* in_sizes, int n_in,
                              void* d_out, int out_size, void* d_ws, size_t ws_size,
                              hipStream_t stream) {
    const float* in  = (const float*)d_in[0];
    const float* emb = (const float*)d_in[1];
    float* out = (float*)d_out;

    ushort* ehi  = (ushort*)d_ws;                   // 1024*64 shorts
    ushort* elo  = ehi + NE * E_DIM;                // 1024*64 shorts
    float* enorm = (float*)(elo + NE * E_DIM);      // 1024 f
    int*   hist  = (int*)(enorm + NE);              // 1024 i
    float* lacc  = (float*)(hist + NE);             // 1 f

    k0_prep<<<16, 256, 0, stream>>>(emb, ehi, elo, enorm, hist, lacc);
    k1_main<<<512, 256, 0, stream>>>(in, emb, ehi, elo, enorm, hist, lacc, out);
    k3_final<<<1, 256, 0, stream>>>(hist, lacc, out);
}